// Round 8
// baseline (289.802 us; speedup 1.0000x reference)
//
#include <hip/hip_runtime.h>

#define HH 384
#define HWPX (HH*HH)

// ws float-offset layout: ws[0..1] = xg (atomicMax), folded weights:
#define WOFF3 16
#define HS3   40      // D=3,  DP=4 : 2*3*4 + 3*4 + 4
#define WOFF6 256     // 16 + 6*40
#define HS6   328     // D=12, DP=12
#define WOFF9 1568    // 256 + 4*328
#define HS9   1828    // D=27, DP=32
#define CATOFF 8192   // cat [2][9][384][384] floats

__device__ __forceinline__ int rx(int g) {
    g = g < 0 ? -g : g;
    return g >= HH ? 2 * HH - 2 - g : g;
}
__device__ __forceinline__ float4 fma4s(float4 a, float4 w, float t) {
    a.x += w.x * t; a.y += w.y * t; a.z += w.z * t; a.w += w.w * t; return a;
}
__device__ __forceinline__ float dot4(float4 a, float4 b) {
    return a.x * b.x + a.y * b.y + a.z * b.z + a.w * b.w;
}
__device__ __forceinline__ float f4c(const float4& v, int j) {
    return j == 0 ? v.x : (j == 1 ? v.y : (j == 2 ? v.z : v.w));
}

// ---------------- k1: fold weights (12 blocks) ----------------
__global__ __launch_bounds__(256) void pre_w(
    const float* __restrict__ w3q, const float* __restrict__ b3q,
    const float* __restrict__ w3k, const float* __restrict__ b3k,
    const float* __restrict__ w3v, const float* __restrict__ b3v, const float* __restrict__ hw3,
    const float* __restrict__ w6q, const float* __restrict__ b6q,
    const float* __restrict__ w6k, const float* __restrict__ b6k,
    const float* __restrict__ w6v, const float* __restrict__ b6v, const float* __restrict__ hw6,
    const float* __restrict__ w9q, const float* __restrict__ b9q,
    const float* __restrict__ w9k, const float* __restrict__ b9k,
    const float* __restrict__ w9v, const float* __restrict__ b9v, const float* __restrict__ hw9,
    float* __restrict__ ws)
{
    const int blk = blockIdx.x;
    const int tid = threadIdx.x;
    int stage = blk < 6 ? 0 : (blk < 10 ? 1 : 2);
    int h = blk - (stage == 0 ? 0 : (stage == 1 ? 6 : 10));
    const float* WQ[3] = {w3q, w6q, w9q};
    const float* BQ[3] = {b3q, b6q, b9q};
    const float* WK[3] = {w3k, w6k, w9k};
    const float* BK[3] = {b3k, b6k, b9k};
    const float* WV_[3] = {w3v, w6v, w9v};
    const float* BV[3] = {b3v, b6v, b9v};
    const float* HWp[3] = {hw3, hw6, hw9};
    const int Ds[3] = {3, 12, 27};
    const int DPs[3] = {4, 12, 32};
    const int WOFFs[3] = {WOFF3, WOFF6, WOFF9};
    const int HSs[3] = {HS3, HS6, HS9};

    const int D = Ds[stage], DP = DPs[stage];
    const float* wq = WQ[stage] + h * D * D;
    const float* bq = BQ[stage] + h * D;
    const float* wk = WK[stage] + h * D * D;
    const float* bk = BK[stage] + h * D;
    const float* wv = WV_[stage] + h * D * D;
    const float* bv = BV[stage] + h * D;
    const float hwv = HWp[stage][h];
    float* base = ws + WOFFs[stage] + h * HSs[stage];
    const float scale = rsqrtf((float)D);

    for (int i = tid; i < D * DP; i += 256) {
        int a = i / DP, b = i % DP;
        float m = 0.f;
        if (b < D) for (int e = 0; e < D; ++e) m += wk[e * D + b] * wq[e * D + a];
        base[i] = scale * m;                       // M[a][d], pad cols = 0
        float wvv = 0.f;
        if (b < D) wvv = hwv * wv[a * D + b];
        base[D * DP + i] = wvv;                    // WV[e][d], pad cols = 0
    }
    for (int i = tid; i < DP; i += 256) {
        float cv = 0.f, uv = 0.f;
        if (i < D) for (int e = 0; e < D; ++e) {
            cv += bq[e] * wk[e * D + i];
            uv += wq[e * D + i] * bk[e];
        }
        base[2 * D * DP + i] = scale * cv;         // c (pad 0)
        base[2 * D * DP + DP + i] = scale * uv;    // u (pad 0)
        base[2 * D * DP + 2 * DP + i] = (i < D) ? hwv * bv[i] : 0.f;   // bvh
    }
    if (tid == 0) {
        float s = 0.f;
        for (int e = 0; e < D; ++e) s += bq[e] * bk[e];
        base[2 * D * DP + 3 * DP] = scale * s;     // s0
    }
}

// ---------------- k2: fused stage3+stage6 (+xg max), block = 8x8 stage6-windows ----------------
__global__ __launch_bounds__(256) void attn36(
    const float* __restrict__ x, float* __restrict__ cat,
    const float* __restrict__ w3f, const float* __restrict__ w6f,
    float* __restrict__ xgws)
{
    __shared__ float sx[1452];                    // [3][22][22]
    __shared__ __align__(16) float sw3[240];
    __shared__ __align__(16) float sw6[1312];
    __shared__ __align__(16) float scell3[1200];  // [10][10] cells x 12
    __shared__ float comb[3072];                  // [4][64][12]

    const int tid = threadIdx.x;
    const int b = blockIdx.z;
    const int BW6X = blockIdx.x * 8, BW6Y = blockIdx.y * 8;
    const int xo = 2 * BW6X - 3, yo = 2 * BW6Y - 3;   // sx origin in x coords
    const float* xb = x + (size_t)b * 3 * HWPX;
    float* catb = cat + (size_t)b * 9 * HWPX;

    // P0: stage x halo (reflect) + weights; fused xg max
    float tmax = 0.f;
    for (int i = tid; i < 1452; i += 256) {
        int c = i / 484, rem = i % 484;
        int ly = rem / 22, lx = rem % 22;
        float v = xb[c * HWPX + rx(yo + ly) * HH + rx(xo + lx)];
        sx[i] = v;
        tmax = fmaxf(tmax, v);
    }
    for (int off = 32; off; off >>= 1) tmax = fmaxf(tmax, __shfl_down(tmax, off));
    if ((tid & 63) == 0) atomicMax((int*)xgws + b, __float_as_int(tmax));  // poison negative; v>=0 wins
    for (int i = tid; i < 60; i += 256) ((float4*)sw3)[i] = ((const float4*)w3f)[i];
    for (int i = tid; i < 328; i += 256) ((float4*)sw6)[i] = ((const float4*)w6f)[i];
    __syncthreads();

    // P1: stage3 over 20x20 X3 pixels (reflected coords for out-of-image)
#pragma unroll 1
    for (int it = 0; it < 2; ++it) {
        const int item = tid + it * 256;
        if (item < 400) {
            const int pyi = item / 20, pxi = item % 20;
            const int gy = 2 * BW6Y - 2 + pyi, gx = 2 * BW6X - 2 + pxi;
            const int gy2 = rx(gy), gx2 = rx(gx);
            const int ly = gy2 - yo, lx = gx2 - xo;
            float4 T[9];
#pragma unroll
            for (int di = 0; di < 3; ++di)
#pragma unroll
                for (int dj = 0; dj < 3; ++dj) {
                    const int o = (ly - 1 + di) * 22 + lx - 1 + dj;
                    T[di * 3 + dj] = make_float4(sx[o], sx[484 + o], sx[968 + o], 0.f);
                }
            float m0 = 0.f, m1 = 0.f, m2 = 0.f;
#pragma unroll 1
            for (int h = 0; h < 6; ++h) {
                const float* hb = &sw3[h * 40];
                float4 qk = *(const float4*)(hb + 24);
                float su = hb[36] + dot4(*(const float4*)(hb + 28), T[4]);
                qk = fma4s(qk, *(const float4*)(hb + 0), T[4].x);
                qk = fma4s(qk, *(const float4*)(hb + 4), T[4].y);
                qk = fma4s(qk, *(const float4*)(hb + 8), T[4].z);
                float den = 0.f; float4 wt = {0.f, 0.f, 0.f, 0.f};
#pragma unroll
                for (int p = 0; p < 9; ++p) {
                    float e = __expf(su + dot4(qk, T[p]));
                    den += e; wt = fma4s(wt, T[p], e);
                }
                const float wi = 1.f / den;
                wt.x *= wi; wt.y *= wi; wt.z *= wi; wt.w *= wi;
                m0 += hb[32] + dot4(*(const float4*)(hb + 12), wt);
                m1 += hb[33] + dot4(*(const float4*)(hb + 16), wt);
                m2 += hb[34] + dot4(*(const float4*)(hb + 20), wt);
            }
            float* cell = &scell3[((pyi >> 1) * 10 + (pxi >> 1)) * 12];
            const int sl = (pyi & 1) * 2 + (pxi & 1);
            cell[sl] = m0; cell[4 + sl] = m1; cell[8 + sl] = m2;
            if (pyi >= 2 && pyi < 18 && pxi >= 2 && pxi < 18) {   // interior: planar X3 for conv
                catb[6 * HWPX + gy * HH + gx] = m0;
                catb[7 * HWPX + gy * HH + gx] = m1;
                catb[8 * HWPX + gy * HH + gx] = m2;
            }
        }
    }
    __syncthreads();

    // P2: stage6, thread = (head, window)
    const int h = tid >> 6, w = tid & 63;
    const int wx = w & 7, wy = w >> 3;
    const float* hb = &sw6[h * HS6];

    const float4* cc4 = (const float4*)&scell3[((wy + 1) * 10 + (wx + 1)) * 12];
    const float4 t40 = cc4[0], t41 = cc4[1], t42 = cc4[2];

    float4 qk0 = *(const float4*)(hb + 288);
    float4 qk1 = *(const float4*)(hb + 292);
    float4 qk2 = *(const float4*)(hb + 296);
    float su = hb[324] + dot4(*(const float4*)(hb + 300), t40)
             + dot4(*(const float4*)(hb + 304), t41)
             + dot4(*(const float4*)(hb + 308), t42);
#pragma unroll
    for (int a = 0; a < 12; ++a) {
        const float t = f4c(a < 4 ? t40 : (a < 8 ? t41 : t42), a & 3);
        const float4* Mr = (const float4*)(hb + 12 * a);
        qk0 = fma4s(qk0, Mr[0], t);
        qk1 = fma4s(qk1, Mr[1], t);
        qk2 = fma4s(qk2, Mr[2], t);
    }
    float den = 0.f;
    float4 wt0 = {0,0,0,0}, wt1 = {0,0,0,0}, wt2 = {0,0,0,0};
#pragma unroll
    for (int p = 0; p < 9; ++p) {
        const int di = p / 3, dj = p % 3;
        const float4* cp = (const float4*)&scell3[((wy + di) * 10 + (wx + dj)) * 12];
        const float4 c0 = cp[0], c1 = cp[1], c2 = cp[2];
        float e = __expf(su + dot4(qk0, c0) + dot4(qk1, c1) + dot4(qk2, c2));
        den += e;
        wt0 = fma4s(wt0, c0, e);
        wt1 = fma4s(wt1, c1, e);
        wt2 = fma4s(wt2, c2, e);
    }
    const float wi = 1.f / den;
    wt0.x *= wi; wt0.y *= wi; wt0.z *= wi; wt0.w *= wi;
    wt1.x *= wi; wt1.y *= wi; wt1.z *= wi; wt1.w *= wi;
    wt2.x *= wi; wt2.y *= wi; wt2.z *= wi; wt2.w *= wi;

    float* cbp = &comb[(h * 64 + w) * 12];
#pragma unroll
    for (int e = 0; e < 12; ++e) {
        const float4* Wr = (const float4*)(hb + 144 + 12 * e);
        cbp[e] = hb[312 + e] + dot4(Wr[0], wt0) + dot4(Wr[1], wt1) + dot4(Wr[2], wt2);
    }
    __syncthreads();

    // P3: combine heads -> planar X6 (ch3-5)
    for (int i = tid; i < 768; i += 256) {
        int w2 = i / 12, e = i % 12;
        float v = comb[w2 * 12 + e] + comb[(64 + w2) * 12 + e]
                + comb[(128 + w2) * 12 + e] + comb[(192 + w2) * 12 + e];
        int c = e >> 2, r = (e >> 1) & 1, s = e & 1;
        int gy = 2 * (BW6Y + (w2 >> 3)) + r, gx = 2 * (BW6X + (w2 & 7)) + s;
        catb[(3 + c) * HWPX + gy * HH + gx] = v;
    }
}

// ---------------- k3: stage9, 4-lane team per (window, head) (round-7, passed) ----------------
__global__ __launch_bounds__(256) void attn9(
    const float* __restrict__ cat, float* __restrict__ catOut,
    const float* __restrict__ wsw)
{
    __shared__ __align__(16) float scell[2160];   // 60 cells x 36 (27..31 zeroed)
    __shared__ __align__(16) float sw[3656];      // 2 x HS9
    __shared__ float comb[1728];                  // [2][32][27]

    const int tid = threadIdx.x;
    const int b = blockIdx.z;
    const int BCX = blockIdx.x * 8, BCY = blockIdx.y * 4;
    const float* inb = cat + (size_t)b * 9 * HWPX + 3 * HWPX;

    for (int i = tid; i < 914; i += 256)
        ((float4*)sw)[i] = ((const float4*)wsw)[i];
    const int by0 = 3 * BCY - 3, bx0 = 3 * BCX - 3;
    for (int i = tid; i < 1620; i += 256) {
        int c = i / 540; int rem = i - c * 540;
        int row = rem / 30, col = rem % 30;
        int gy = rx(by0 + row), gx = rx(bx0 + col);
        scell[((row / 3) * 10 + (col / 3)) * 36 + c * 9 + (row % 3) * 3 + (col % 3)]
            = inb[c * HWPX + gy * HH + gx];
    }
    for (int i = tid; i < 300; i += 256) scell[(i / 5) * 36 + 27 + (i % 5)] = 0.f;
    __syncthreads();

    const int t = tid & 3, team = tid >> 2;
    const int h = team >> 5, w = team & 31;
    const int wx = w & 7, wy = w >> 3;
    const int k0 = t, k1 = t + 4;
    const float* hb = &sw[h * HS9];

    const float4* cc4 = (const float4*)&scell[((wy + 1) * 10 + (wx + 1)) * 36];
    float4 t4r[8];
#pragma unroll
    for (int k = 0; k < 8; ++k) t4r[k] = cc4[k];

    float4 qk0 = *(const float4*)(hb + 1728 + 4 * k0);
    float4 qk1 = *(const float4*)(hb + 1728 + 4 * k1);
#pragma unroll
    for (int a = 0; a < 27; ++a) {
        const float tv = f4c(t4r[a >> 2], a & 3);
        qk0 = fma4s(qk0, *(const float4*)(hb + a * 32 + 4 * k0), tv);
        qk1 = fma4s(qk1, *(const float4*)(hb + a * 32 + 4 * k1), tv);
    }
    float upart = dot4(*(const float4*)(hb + 1760 + 4 * k0), cc4[k0])
                + dot4(*(const float4*)(hb + 1760 + 4 * k1), cc4[k1]);
    const float s0v = hb[1824];

    float den = 0.f;
    float4 wt0 = {0,0,0,0}, wt1 = {0,0,0,0};
#pragma unroll
    for (int p = 0; p < 9; ++p) {
        const int di = p / 3, dj = p % 3;
        const float4* cp = (const float4*)&scell[((wy + di) * 10 + (wx + dj)) * 36];
        const float4 c0 = cp[k0], c1 = cp[k1];
        float part = upart + dot4(qk0, c0) + dot4(qk1, c1);
        part += __shfl_xor(part, 1);
        part += __shfl_xor(part, 2);
        const float e = __expf(s0v + part);
        den += e;
        wt0 = fma4s(wt0, c0, e);
        wt1 = fma4s(wt1, c1, e);
    }
    const float wi = 1.f / den;
    wt0.x *= wi; wt0.y *= wi; wt0.z *= wi; wt0.w *= wi;
    wt1.x *= wi; wt1.y *= wi; wt1.z *= wi; wt1.w *= wi;

    float* cbp = &comb[(h * 32 + w) * 27];
#pragma unroll
    for (int e = 0; e < 27; ++e) {
        float po = dot4(*(const float4*)(hb + 864 + e * 32 + 4 * k0), wt0)
                 + dot4(*(const float4*)(hb + 864 + e * 32 + 4 * k1), wt1);
        po += __shfl_xor(po, 1);
        po += __shfl_xor(po, 2);
        if (t == 0) cbp[e] = po + hb[1792 + e];
    }
    __syncthreads();

    float* outb = catOut + (size_t)b * 9 * HWPX;
    for (int i = tid; i < 864; i += 256) {
        int w2 = i / 27, e = i % 27;
        float v = comb[w2 * 27 + e] + comb[(32 + w2) * 27 + e];
        int c = e / 9, r = (e % 9) / 3, s = e % 3;
        int gy = 3 * (BCY + (w2 >> 3)) + r, gx = 3 * (BCX + (w2 & 7)) + s;
        outb[c * HWPX + gy * HH + gx] = v;
    }
}

// ---------------- k4: conv0 (5x5, zero-pad 2) + final; 16x16 tile, 128 thr, 2 px/thread ----------------
__global__ __launch_bounds__(128) void conv_final(
    const float* __restrict__ cat, const float* __restrict__ cw,
    const float* __restrict__ cb, const float* __restrict__ x,
    const float* __restrict__ xg, float* __restrict__ out)
{
    __shared__ float tile[9][20][24];
    __shared__ float sw[678];
    const int tid = threadIdx.x;
    const int b = blockIdx.z;
    const int bx = blockIdx.x * 16, by = blockIdx.y * 16;
    const float* catb = cat + (size_t)b * 9 * HWPX;

    for (int i = tid; i < 678; i += 128) sw[i] = (i < 675) ? cw[i] : cb[i - 675];
    for (int i = tid; i < 1080; i += 128) {
        int ci = i / 120, rem = i % 120;
        int row = rem / 6, c4 = rem % 6;
        int y = by + row - 2, xx = bx - 4 + 4 * c4;
        float4 v = {0.f, 0.f, 0.f, 0.f};
        if (y >= 0 && y < HH && xx >= 0 && xx <= HH - 4)
            v = *(const float4*)&catb[ci * HWPX + y * HH + xx];
        *(float4*)&tile[ci][row][4 * c4] = v;
    }
    __syncthreads();

    const int lx = tid & 15, ly0 = (tid >> 4) * 2;
    float acc[2][3];
    acc[0][0] = acc[1][0] = sw[675];
    acc[0][1] = acc[1][1] = sw[676];
    acc[0][2] = acc[1][2] = sw[677];

#pragma unroll 1
    for (int ci = 0; ci < 9; ++ci) {
        float rv[6][5];
#pragma unroll
        for (int rr = 0; rr < 6; ++rr)
#pragma unroll
            for (int cc = 0; cc < 5; ++cc)
                rv[rr][cc] = tile[ci][ly0 + rr][lx + 2 + cc];
#pragma unroll
        for (int ky = 0; ky < 5; ++ky)
#pragma unroll
            for (int kx = 0; kx < 5; ++kx) {
                const float w0 = sw[(0 * 9 + ci) * 25 + ky * 5 + kx];
                const float w1 = sw[(1 * 9 + ci) * 25 + ky * 5 + kx];
                const float w2 = sw[(2 * 9 + ci) * 25 + ky * 5 + kx];
                const float ta = rv[ky][kx], tb = rv[ky + 1][kx];
                acc[0][0] += ta * w0; acc[0][1] += ta * w1; acc[0][2] += ta * w2;
                acc[1][0] += tb * w0; acc[1][1] += tb * w1; acc[1][2] += tb * w2;
            }
    }

    const float xgv = xg[b];
#pragma unroll
    for (int jj = 0; jj < 2; ++jj) {
        const int gy = by + ly0 + jj, gx = bx + lx;
#pragma unroll
        for (int co = 0; co < 3; ++co) {
            const float x0 = fmaxf(acc[jj][co], 0.f);
            const float xv = x[((size_t)(b * 3 + co)) * HWPX + gy * HH + gx];
            out[((size_t)(b * 3 + co)) * HWPX + gy * HH + gx] =
                fmaxf(xv * x0 + xgv - x0, 0.f);
        }
    }
}

// ---------------- launch ----------------
extern "C" void kernel_launch(void* const* d_in, const int* in_sizes, int n_in,
                              void* d_out, int out_size, void* d_ws, size_t ws_size,
                              hipStream_t stream) {
    const float* x   = (const float*)d_in[0];
    const float* w3q = (const float*)d_in[1];
    const float* b3q = (const float*)d_in[2];
    const float* w3k = (const float*)d_in[3];
    const float* b3k = (const float*)d_in[4];
    const float* w3v = (const float*)d_in[5];
    const float* b3v = (const float*)d_in[6];
    const float* hw3 = (const float*)d_in[7];
    const float* w6q = (const float*)d_in[8];
    const float* b6q = (const float*)d_in[9];
    const float* w6k = (const float*)d_in[10];
    const float* b6k = (const float*)d_in[11];
    const float* w6v = (const float*)d_in[12];
    const float* b6v = (const float*)d_in[13];
    const float* hw6 = (const float*)d_in[14];
    const float* w9q = (const float*)d_in[15];
    const float* b9q = (const float*)d_in[16];
    const float* w9k = (const float*)d_in[17];
    const float* b9k = (const float*)d_in[18];
    const float* w9v = (const float*)d_in[19];
    const float* b9v = (const float*)d_in[20];
    const float* hw9 = (const float*)d_in[21];
    const float* c0w = (const float*)d_in[22];
    const float* c0b = (const float*)d_in[23];

    float* out = (float*)d_out;
    float* ws  = (float*)d_ws;
    float* cat = ws + CATOFF;

    pre_w<<<12, 256, 0, stream>>>(
        w3q, b3q, w3k, b3k, w3v, b3v, hw3,
        w6q, b6q, w6k, b6k, w6v, b6v, hw6,
        w9q, b9q, w9k, b9k, w9v, b9v, hw9, ws);

    // fused stage3+stage6 (+xg) -> cat ch6-8 (X3) and ch3-5 (X6)
    attn36<<<dim3(24, 24, 2), 256, 0, stream>>>(
        x, cat, ws + WOFF3, ws + WOFF6, ws);
    // stage9 -> cat ch0-2
    attn9<<<dim3(16, 32, 2), 256, 0, stream>>>(cat, cat, ws + WOFF9);

    conv_final<<<dim3(24, 24, 2), 128, 0, stream>>>(cat, c0w, c0b, x, ws, out);
}

// Round 9
// 208.833 us; speedup vs baseline: 1.3877x; 1.3877x over previous
//
#include <hip/hip_runtime.h>

#define HH 384
#define HWPX (HH*HH)

// ws float-offset layout: ws[0..1] = xg (atomicMax), folded weights:
#define WOFF3 16
#define HS3   40      // D=3,  DP=4 : 2*3*4 + 3*4 + 4
#define WOFF6 256     // 16 + 6*40
#define HS6   328     // D=12, DP=12
#define WOFF9 1568    // 256 + 4*328
#define HS9   1828    // D=27, DP=32
#define CATOFF 8192   // cat [2][9][384][384] floats

__device__ __forceinline__ int rx(int g) {
    g = g < 0 ? -g : g;
    return g >= HH ? 2 * HH - 2 - g : g;
}
__device__ __forceinline__ float4 fma4s(float4 a, float4 w, float t) {
    a.x += w.x * t; a.y += w.y * t; a.z += w.z * t; a.w += w.w * t; return a;
}
__device__ __forceinline__ float dot4(float4 a, float4 b) {
    return a.x * b.x + a.y * b.y + a.z * b.z + a.w * b.w;
}
__device__ __forceinline__ float f4c(const float4& v, int j) {
    return j == 0 ? v.x : (j == 1 ? v.y : (j == 2 ? v.z : v.w));
}

// ---------------- k1: fold weights (blocks 0..11) + xg max (blocks 12..299) ----------------
__global__ __launch_bounds__(256) void pre_xg(
    const float* __restrict__ w3q, const float* __restrict__ b3q,
    const float* __restrict__ w3k, const float* __restrict__ b3k,
    const float* __restrict__ w3v, const float* __restrict__ b3v, const float* __restrict__ hw3,
    const float* __restrict__ w6q, const float* __restrict__ b6q,
    const float* __restrict__ w6k, const float* __restrict__ b6k,
    const float* __restrict__ w6v, const float* __restrict__ b6v, const float* __restrict__ hw6,
    const float* __restrict__ w9q, const float* __restrict__ b9q,
    const float* __restrict__ w9k, const float* __restrict__ b9k,
    const float* __restrict__ w9v, const float* __restrict__ b9v, const float* __restrict__ hw9,
    const float* __restrict__ x, float* __restrict__ ws)
{
    __shared__ float sm[4];
    const int blk = blockIdx.x;
    const int tid = threadIdx.x;

    if (blk < 12) {
        int stage = blk < 6 ? 0 : (blk < 10 ? 1 : 2);
        int h = blk - (stage == 0 ? 0 : (stage == 1 ? 6 : 10));
        const float* WQ[3] = {w3q, w6q, w9q};
        const float* BQ[3] = {b3q, b6q, b9q};
        const float* WK[3] = {w3k, w6k, w9k};
        const float* BK[3] = {b3k, b6k, b9k};
        const float* WV_[3] = {w3v, w6v, w9v};
        const float* BV[3] = {b3v, b6v, b9v};
        const float* HWp[3] = {hw3, hw6, hw9};
        const int Ds[3] = {3, 12, 27};
        const int DPs[3] = {4, 12, 32};
        const int WOFFs[3] = {WOFF3, WOFF6, WOFF9};
        const int HSs[3] = {HS3, HS6, HS9};

        const int D = Ds[stage], DP = DPs[stage];
        const float* wq = WQ[stage] + h * D * D;
        const float* bq = BQ[stage] + h * D;
        const float* wk = WK[stage] + h * D * D;
        const float* bk = BK[stage] + h * D;
        const float* wv = WV_[stage] + h * D * D;
        const float* bv = BV[stage] + h * D;
        const float hwv = HWp[stage][h];
        float* base = ws + WOFFs[stage] + h * HSs[stage];
        const float scale = rsqrtf((float)D);

        for (int i = tid; i < D * DP; i += 256) {
            int a = i / DP, b = i % DP;
            float m = 0.f;
            if (b < D) for (int e = 0; e < D; ++e) m += wk[e * D + b] * wq[e * D + a];
            base[i] = scale * m;                       // M[a][d], pad cols = 0
            float wvv = 0.f;
            if (b < D) wvv = hwv * wv[a * D + b];
            base[D * DP + i] = wvv;                    // WV[e][d], pad cols = 0
        }
        for (int i = tid; i < DP; i += 256) {
            float cv = 0.f, uv = 0.f;
            if (i < D) for (int e = 0; e < D; ++e) {
                cv += bq[e] * wk[e * D + i];
                uv += wq[e * D + i] * bk[e];
            }
            base[2 * D * DP + i] = scale * cv;         // c (pad 0)
            base[2 * D * DP + DP + i] = scale * uv;    // u (pad 0)
            base[2 * D * DP + 2 * DP + i] = (i < D) ? hwv * bv[i] : 0.f;   // bvh
        }
        if (tid == 0) {
            float s = 0.f;
            for (int e = 0; e < D; ++e) s += bq[e] * bk[e];
            base[2 * D * DP + 3 * DP] = scale * s;     // s0
        }
    } else {
        int i2 = blk - 12;
        int b = i2 / 144, chunk = i2 % 144;
        const float4* xb = (const float4*)(x + (size_t)b * 3 * HWPX + chunk * 3072);
        float m = 0.f;
        for (int j = tid; j < 768; j += 256) {
            float4 v = xb[j];
            m = fmaxf(m, fmaxf(fmaxf(v.x, v.y), fmaxf(v.z, v.w)));
        }
        for (int off = 32; off; off >>= 1)
            m = fmaxf(m, __shfl_down(m, off));
        if ((tid & 63) == 0) sm[tid >> 6] = m;
        __syncthreads();
        if (tid == 0) {
            float mm = fmaxf(fmaxf(sm[0], sm[1]), fmaxf(sm[2], sm[3]));
            atomicMax((int*)&ws[b], __float_as_int(mm));  // poison negative; mm>=0 wins
        }
    }
}

// ---------------- k2: stage3, thread = (window, head); 7x6 windows x 6 heads ----------------
__global__ __launch_bounds__(256) void attn3_hs(
    const float* __restrict__ x, float* __restrict__ cat,
    const float* __restrict__ wsw)
{
    __shared__ float sx[216];                     // [3][8][9]
    __shared__ __align__(16) float sw3[240];
    __shared__ float comb[756];                   // [6][42][3]

    const int tid = threadIdx.x;
    const int b = blockIdx.z;
    const int X0 = blockIdx.x * 7, Y0 = blockIdx.y * 6;
    const float* xb = x + (size_t)b * 3 * HWPX;
    float* catb = cat + (size_t)b * 9 * HWPX;

    if (tid < 216) {
        int c = tid / 72, rem = tid % 72;
        int ty = rem / 9, tx = rem % 9;
        sx[tid] = xb[c * HWPX + rx(Y0 - 1 + ty) * HH + rx(X0 - 1 + tx)];
    }
    if (tid < 60) ((float4*)sw3)[tid] = ((const float4*)wsw)[tid];
    __syncthreads();

    if (tid < 252) {
        const int w = tid % 42, h = tid / 42;
        const int wy = w / 7, wx = w % 7;
        float4 T[9];
#pragma unroll
        for (int di = 0; di < 3; ++di)
#pragma unroll
            for (int dj = 0; dj < 3; ++dj) {
                const int o = (wy + di) * 9 + wx + dj;
                T[di * 3 + dj] = make_float4(sx[o], sx[72 + o], sx[144 + o], 0.f);
            }
        const float* hb = &sw3[h * 40];
        float4 qk = *(const float4*)(hb + 24);
        float su = hb[36] + dot4(*(const float4*)(hb + 28), T[4]);
        qk = fma4s(qk, *(const float4*)(hb + 0), T[4].x);
        qk = fma4s(qk, *(const float4*)(hb + 4), T[4].y);
        qk = fma4s(qk, *(const float4*)(hb + 8), T[4].z);
        float den = 0.f; float4 wt = {0.f, 0.f, 0.f, 0.f};
#pragma unroll
        for (int p = 0; p < 9; ++p) {
            float e = __expf(su + dot4(qk, T[p]));
            den += e; wt = fma4s(wt, T[p], e);
        }
        const float wi = 1.f / den;
        wt.x *= wi; wt.y *= wi; wt.z *= wi; wt.w *= wi;
        float* cb = &comb[(h * 42 + w) * 3];
        cb[0] = hb[32] + dot4(*(const float4*)(hb + 12), wt);
        cb[1] = hb[33] + dot4(*(const float4*)(hb + 16), wt);
        cb[2] = hb[34] + dot4(*(const float4*)(hb + 20), wt);
    }
    __syncthreads();

    if (tid < 126) {
        const int w = tid / 3, c = tid % 3;
        const int gx = X0 + w % 7;
        if (gx < HH) {
            float v = comb[w * 3 + c];
#pragma unroll
            for (int h = 1; h < 6; ++h) v += comb[(h * 42 + w) * 3 + c];
            catb[(6 + c) * HWPX + (Y0 + w / 7) * HH + gx] = v;
        }
    }
}

// ---------------- k3: stage6, thread = (window, head); 8x8 win x 4 heads ----------------
__global__ __launch_bounds__(256) void attn6(
    const float* __restrict__ cat, float* __restrict__ catOut,
    const float* __restrict__ wsw)
{
    __shared__ __align__(16) float scell[1200];   // 10x10 cells x 12
    __shared__ __align__(16) float sw[1312];      // 4 x HS6
    __shared__ float comb[3072];                  // [4][64][12]

    const int tid = threadIdx.x;
    const int b = blockIdx.z;
    const int BCX = blockIdx.x * 8, BCY = blockIdx.y * 8;
    const float* inb = cat + (size_t)b * 9 * HWPX + 6 * HWPX;   // X3 (ch6-8)

    for (int i = tid; i < 328; i += 256)
        ((float4*)sw)[i] = ((const float4*)wsw)[i];
    const int by0 = 2 * BCY - 2, bx0 = 2 * BCX - 2;
    for (int i = tid; i < 1200; i += 256) {
        int c = i / 400; int rem = i - c * 400;
        int row = rem / 20, col = rem % 20;
        int gy = rx(by0 + row), gx = rx(bx0 + col);
        scell[((row >> 1) * 10 + (col >> 1)) * 12 + c * 4 + (row & 1) * 2 + (col & 1)]
            = inb[c * HWPX + gy * HH + gx];
    }
    __syncthreads();

    const int h = tid >> 6, w = tid & 63;
    const int wx = w & 7, wy = w >> 3;
    const float* hb = &sw[h * HS6];

    const float4* cc4 = (const float4*)&scell[((wy + 1) * 10 + (wx + 1)) * 12];
    const float4 t40 = cc4[0], t41 = cc4[1], t42 = cc4[2];

    float4 qk0 = *(const float4*)(hb + 288);
    float4 qk1 = *(const float4*)(hb + 292);
    float4 qk2 = *(const float4*)(hb + 296);
    float su = hb[324] + dot4(*(const float4*)(hb + 300), t40)
             + dot4(*(const float4*)(hb + 304), t41)
             + dot4(*(const float4*)(hb + 308), t42);
#pragma unroll
    for (int a = 0; a < 12; ++a) {
        const float t = f4c(a < 4 ? t40 : (a < 8 ? t41 : t42), a & 3);
        const float4* Mr = (const float4*)(hb + 12 * a);
        qk0 = fma4s(qk0, Mr[0], t);
        qk1 = fma4s(qk1, Mr[1], t);
        qk2 = fma4s(qk2, Mr[2], t);
    }
    float den = 0.f;
    float4 wt0 = {0,0,0,0}, wt1 = {0,0,0,0}, wt2 = {0,0,0,0};
#pragma unroll
    for (int p = 0; p < 9; ++p) {
        const int di = p / 3, dj = p % 3;
        const float4* cp = (const float4*)&scell[((wy + di) * 10 + (wx + dj)) * 12];
        const float4 c0 = cp[0], c1 = cp[1], c2 = cp[2];
        float e = __expf(su + dot4(qk0, c0) + dot4(qk1, c1) + dot4(qk2, c2));
        den += e;
        wt0 = fma4s(wt0, c0, e);
        wt1 = fma4s(wt1, c1, e);
        wt2 = fma4s(wt2, c2, e);
    }
    const float wi = 1.f / den;
    wt0.x *= wi; wt0.y *= wi; wt0.z *= wi; wt0.w *= wi;
    wt1.x *= wi; wt1.y *= wi; wt1.z *= wi; wt1.w *= wi;
    wt2.x *= wi; wt2.y *= wi; wt2.z *= wi; wt2.w *= wi;

    float* cbp = &comb[(h * 64 + w) * 12];
#pragma unroll
    for (int e = 0; e < 12; ++e) {
        const float4* Wr = (const float4*)(hb + 144 + 12 * e);
        cbp[e] = hb[312 + e] + dot4(Wr[0], wt0) + dot4(Wr[1], wt1) + dot4(Wr[2], wt2);
    }
    __syncthreads();

    float* outb = catOut + (size_t)b * 9 * HWPX + 3 * HWPX;   // ch3-5
    for (int i = tid; i < 768; i += 256) {
        int w2 = i / 12, e = i % 12;
        float v = comb[w2 * 12 + e] + comb[(64 + w2) * 12 + e]
                + comb[(128 + w2) * 12 + e] + comb[(192 + w2) * 12 + e];
        int c = e >> 2, r = (e >> 1) & 1, s = e & 1;
        int gy = 2 * (BCY + (w2 >> 3)) + r, gx = 2 * (BCX + (w2 & 7)) + s;
        outb[c * HWPX + gy * HH + gx] = v;
    }
}

// ---------------- k4: stage9, 4-lane team per (window, head); LDS wt round-trip ----------------
__global__ __launch_bounds__(256) void attn9(
    const float* __restrict__ cat, float* __restrict__ catOut,
    const float* __restrict__ wsw)
{
    __shared__ __align__(16) float scell[2160];   // 60 cells x 36 (27..31 zeroed)
    __shared__ __align__(16) float sw[3656];      // 2 x HS9
    __shared__ float comb[1728];                  // [2][32][27]
    __shared__ __align__(16) float twt[2048];     // [64 teams][32]

    const int tid = threadIdx.x;
    const int b = blockIdx.z;
    const int BCX = blockIdx.x * 8, BCY = blockIdx.y * 4;
    const float* inb = cat + (size_t)b * 9 * HWPX + 3 * HWPX;

    for (int i = tid; i < 914; i += 256)
        ((float4*)sw)[i] = ((const float4*)wsw)[i];
    const int by0 = 3 * BCY - 3, bx0 = 3 * BCX - 3;
    for (int i = tid; i < 1620; i += 256) {
        int c = i / 540; int rem = i - c * 540;
        int row = rem / 30, col = rem % 30;
        int gy = rx(by0 + row), gx = rx(bx0 + col);
        scell[((row / 3) * 10 + (col / 3)) * 36 + c * 9 + (row % 3) * 3 + (col % 3)]
            = inb[c * HWPX + gy * HH + gx];
    }
    for (int i = tid; i < 300; i += 256) scell[(i / 5) * 36 + 27 + (i % 5)] = 0.f;
    __syncthreads();

    const int t = tid & 3, team = tid >> 2;       // 64 teams: h = team>>5, w = team&31
    const int h = team >> 5, w = team & 31;
    const int wx = w & 7, wy = w >> 3;
    const int k0 = t, k1 = t + 4;
    const float* hb = &sw[h * HS9];

    const float4* cc4 = (const float4*)&scell[((wy + 1) * 10 + (wx + 1)) * 36];
    float4 t4r[8];
#pragma unroll
    for (int k = 0; k < 8; ++k) t4r[k] = cc4[k];

    float4 qk0 = *(const float4*)(hb + 1728 + 4 * k0);
    float4 qk1 = *(const float4*)(hb + 1728 + 4 * k1);
#pragma unroll
    for (int a = 0; a < 27; ++a) {
        const float tv = f4c(t4r[a >> 2], a & 3);
        qk0 = fma4s(qk0, *(const float4*)(hb + a * 32 + 4 * k0), tv);
        qk1 = fma4s(qk1, *(const float4*)(hb + a * 32 + 4 * k1), tv);
    }
    float upart = dot4(*(const float4*)(hb + 1760 + 4 * k0), cc4[k0])
                + dot4(*(const float4*)(hb + 1760 + 4 * k1), cc4[k1]);
    const float s0v = hb[1824];

    float den = 0.f;
    float4 wt0 = {0,0,0,0}, wt1 = {0,0,0,0};
#pragma unroll
    for (int p = 0; p < 9; ++p) {
        const int di = p / 3, dj = p % 3;
        const float4* cp = (const float4*)&scell[((wy + di) * 10 + (wx + dj)) * 36];
        const float4 c0 = cp[k0], c1 = cp[k1];
        float part = upart + dot4(qk0, c0) + dot4(qk1, c1);
        part += __shfl_xor(part, 1);
        part += __shfl_xor(part, 2);
        const float e = __expf(s0v + part);
        den += e;
        wt0 = fma4s(wt0, c0, e);
        wt1 = fma4s(wt1, c1, e);
    }
    const float wi = 1.f / den;
    wt0.x *= wi; wt0.y *= wi; wt0.z *= wi; wt0.w *= wi;
    wt1.x *= wi; wt1.y *= wi; wt1.z *= wi; wt1.w *= wi;

    // share wt within team via LDS (no syncthreads needed: same wave)
    float4* tw = (float4*)&twt[team * 32];
    tw[k0] = wt0;
    tw[k1] = wt1;
    float4 W[7];
#pragma unroll
    for (int k = 0; k < 7; ++k) W[k] = tw[k];

    // each lane computes e = t, t+4, ... (7 dims, guard e<27)
    float* cbp = &comb[(h * 32 + w) * 27];
#pragma unroll
    for (int ei = 0; ei < 7; ++ei) {
        const int e = t + 4 * ei;
        if (e < 27) {
            const float4* Wr = (const float4*)(hb + 864 + e * 32);
            float po = hb[1792 + e];
#pragma unroll
            for (int k = 0; k < 7; ++k) po += dot4(Wr[k], W[k]);
            cbp[e] = po;
        }
    }
    __syncthreads();

    float* outb = catOut + (size_t)b * 9 * HWPX;
    for (int i = tid; i < 864; i += 256) {
        int w2 = i / 27, e = i % 27;
        float v = comb[w2 * 27 + e] + comb[(32 + w2) * 27 + e];
        int c = e / 9, r = (e % 9) / 3, s = e % 3;
        int gy = 3 * (BCY + (w2 >> 3)) + r, gx = 3 * (BCX + (w2 & 7)) + s;
        outb[c * HWPX + gy * HH + gx] = v;
    }
}

// ---------------- k5: conv0 (5x5, zero-pad 2) + final; 16x16 tile, 256 thr, 1 px/thread ----------------
__global__ __launch_bounds__(256) void conv_final(
    const float* __restrict__ cat, const float* __restrict__ cw,
    const float* __restrict__ cb, const float* __restrict__ x,
    const float* __restrict__ xg, float* __restrict__ out)
{
    __shared__ __align__(16) float tile[9][20][24];
    __shared__ float sw[678];
    const int tid = threadIdx.x;
    const int b = blockIdx.z;
    const int bx = blockIdx.x * 16, by = blockIdx.y * 16;
    const float* catb = cat + (size_t)b * 9 * HWPX;

    for (int i = tid; i < 678; i += 256) sw[i] = (i < 675) ? cw[i] : cb[i - 675];
    for (int i = tid; i < 1080; i += 256) {
        int ci = i / 120, rem = i % 120;
        int row = rem / 6, c4 = rem % 6;
        int y = by + row - 2, xx = bx - 4 + 4 * c4;
        float4 v = {0.f, 0.f, 0.f, 0.f};
        if (y >= 0 && y < HH && xx >= 0 && xx <= HH - 4)
            v = *(const float4*)&catb[ci * HWPX + y * HH + xx];
        *(float4*)&tile[ci][row][4 * c4] = v;
    }
    __syncthreads();

    const int lx = tid & 15, ly = tid >> 4;
    float a0 = sw[675], a1 = sw[676], a2 = sw[677];

#pragma unroll 1
    for (int ci = 0; ci < 9; ++ci) {
        float rv[5][5];
#pragma unroll
        for (int ky = 0; ky < 5; ++ky)
#pragma unroll
            for (int kx = 0; kx < 5; ++kx)
                rv[ky][kx] = tile[ci][ly + ky][lx + 2 + kx];
#pragma unroll
        for (int ky = 0; ky < 5; ++ky)
#pragma unroll
            for (int kx = 0; kx < 5; ++kx) {
                const float tv = rv[ky][kx];
                a0 += tv * sw[(0 * 9 + ci) * 25 + ky * 5 + kx];
                a1 += tv * sw[(1 * 9 + ci) * 25 + ky * 5 + kx];
                a2 += tv * sw[(2 * 9 + ci) * 25 + ky * 5 + kx];
            }
    }

    const float xgv = xg[b];
    const int gy = by + ly, gx = bx + lx;
    float acc[3] = {a0, a1, a2};
#pragma unroll
    for (int co = 0; co < 3; ++co) {
        const float x0 = fmaxf(acc[co], 0.f);
        const float xv = x[((size_t)(b * 3 + co)) * HWPX + gy * HH + gx];
        out[((size_t)(b * 3 + co)) * HWPX + gy * HH + gx] =
            fmaxf(xv * x0 + xgv - x0, 0.f);
    }
}

// ---------------- launch ----------------
extern "C" void kernel_launch(void* const* d_in, const int* in_sizes, int n_in,
                              void* d_out, int out_size, void* d_ws, size_t ws_size,
                              hipStream_t stream) {
    const float* x   = (const float*)d_in[0];
    const float* w3q = (const float*)d_in[1];
    const float* b3q = (const float*)d_in[2];
    const float* w3k = (const float*)d_in[3];
    const float* b3k = (const float*)d_in[4];
    const float* w3v = (const float*)d_in[5];
    const float* b3v = (const float*)d_in[6];
    const float* hw3 = (const float*)d_in[7];
    const float* w6q = (const float*)d_in[8];
    const float* b6q = (const float*)d_in[9];
    const float* w6k = (const float*)d_in[10];
    const float* b6k = (const float*)d_in[11];
    const float* w6v = (const float*)d_in[12];
    const float* b6v = (const float*)d_in[13];
    const float* hw6 = (const float*)d_in[14];
    const float* w9q = (const float*)d_in[15];
    const float* b9q = (const float*)d_in[16];
    const float* w9k = (const float*)d_in[17];
    const float* b9k = (const float*)d_in[18];
    const float* w9v = (const float*)d_in[19];
    const float* b9v = (const float*)d_in[20];
    const float* hw9 = (const float*)d_in[21];
    const float* c0w = (const float*)d_in[22];
    const float* c0b = (const float*)d_in[23];

    float* out = (float*)d_out;
    float* ws  = (float*)d_ws;
    float* cat = ws + CATOFF;

    pre_xg<<<300, 256, 0, stream>>>(
        w3q, b3q, w3k, b3k, w3v, b3v, hw3,
        w6q, b6q, w6k, b6k, w6v, b6v, hw6,
        w9q, b9q, w9k, b9k, w9v, b9v, hw9, x, ws);

    // stage3: (window, head) threads -> cat ch6-8
    attn3_hs<<<dim3(55, 64, 2), 256, 0, stream>>>(x, cat, ws + WOFF3);
    // stage6: (window, head) threads -> cat ch3-5
    attn6<<<dim3(24, 24, 2), 256, 0, stream>>>(cat, cat, ws + WOFF6);
    // stage9: 4-lane teams -> cat ch0-2
    attn9<<<dim3(16, 32, 2), 256, 0, stream>>>(cat, cat, ws + WOFF9);

    conv_final<<<dim3(24, 24, 2), 256, 0, stream>>>(cat, c0w, c0b, x, ws, out);
}